// Round 2
// baseline (1109.212 us; speedup 1.0000x reference)
//
#include <hip/hip_runtime.h>

#define D_ 64
#define H_ 128
#define W_ 128
#define C_ 32
#define N_ 2

// block tile (outputs)
#define TD 8
#define TH 8
#define TW 32
// LDS tile (with halo 3 on each side)
#define LDS_D 14
#define LDS_H 14
#define LDS_W 38
#define PITCH 44   // padded row pitch: 16B-aligned rows, spreads banks

__global__ __launch_bounds__(256, 4) void replk3d_kernel(
    const float* __restrict__ x,
    const float* __restrict__ w7, const float* __restrict__ w3, const float* __restrict__ w1,
    const float* __restrict__ g7, const float* __restrict__ b7, const float* __restrict__ m7, const float* __restrict__ v7,
    const float* __restrict__ g3, const float* __restrict__ b3, const float* __restrict__ m3, const float* __restrict__ v3,
    const float* __restrict__ g1, const float* __restrict__ b1, const float* __restrict__ m1, const float* __restrict__ v1,
    float* __restrict__ out)
{
    __shared__ __align__(16) float tile[LDS_D * LDS_H * PITCH]; // 14*14*44 floats = 33.7 KB
    __shared__ __align__(16) float wl7[7 * 52];                 // padded 49->52 per kd plane
    __shared__ __align__(16) float wl3[27];

    const int bx = blockIdx.x;        // 512 tiles per (n,c) slab
    const int slab = blockIdx.y;      // 64 slabs
    const int c = slab & 31;
    const int n = slab >> 5;
    const int tx = bx & 3;            // w tile (4)
    const int ty = (bx >> 2) & 15;    // h tile (16)
    const int tz = bx >> 6;           // d tile (8)
    const int w0 = tx * TW, h0 = ty * TH, d0 = tz * TD;

    const int tid = threadIdx.x;

    // ---- stage weights into LDS ----
    // BUGFIX (r1): block has 256 threads; 343 weight elems need a strided loop,
    // and the old `else if (tid < 370)` branch for wl3 was dead code.
    for (int s = tid; s < 343; s += 256)
        wl7[(s / 49) * 52 + (s % 49)] = w7[c * 343 + s];
    if (tid < 27)
        wl3[tid] = w3[c * 27 + tid];

    // ---- stage input tile (with zero halo) ----
    const float* xc = x + (size_t)(n * C_ + c) * (D_ * H_ * W_);
    for (int s = tid; s < LDS_D * LDS_H * LDS_W; s += 256) {
        int ww = s % LDS_W;
        int t  = s / LDS_W;
        int hh = t % LDS_H;
        int dd = t / LDS_H;
        int gd = d0 - 3 + dd, gh = h0 - 3 + hh, gw = w0 - 3 + ww;
        float v = 0.f;
        if ((unsigned)gd < (unsigned)D_ && (unsigned)gh < (unsigned)H_ && (unsigned)gw < (unsigned)W_)
            v = xc[(size_t)gd * (H_ * W_) + gh * W_ + gw];
        tile[(dd * LDS_H + hh) * PITCH + ww] = v;
    }
    __syncthreads();

    // thread -> output mapping: 8 consecutive w at fixed (d,h)
    const int ttw = tid & 3;          // 4 w-groups of 8
    const int tth = (tid >> 2) & 7;   // 8 h
    const int ttd = tid >> 5;         // 8 d
    const int wloc = ttw * 8;         // LDS w base (out w center = wloc+3+j)

    float acc7[8], acc3[8];
#pragma unroll
    for (int j = 0; j < 8; j++) { acc7[j] = 0.f; acc3[j] = 0.f; }

    // ---- 7x7x7 depthwise ----
#pragma unroll 1
    for (int kd = 0; kd < 7; kd++) {
        float wv[49];
#pragma unroll
        for (int i = 0; i < 12; i++) {
            float4 t4 = *(const float4*)&wl7[kd * 52 + i * 4];
            wv[i * 4 + 0] = t4.x; wv[i * 4 + 1] = t4.y;
            wv[i * 4 + 2] = t4.z; wv[i * 4 + 3] = t4.w;
        }
        wv[48] = wl7[kd * 52 + 48];
        const float* pl = &tile[((ttd + kd) * LDS_H + tth) * PITCH + wloc];
#pragma unroll
        for (int kh = 0; kh < 7; kh++) {
            const float* rp = pl + kh * PITCH;
            float4 a  = *(const float4*)(rp);
            float4 b  = *(const float4*)(rp + 4);
            float4 cc = *(const float4*)(rp + 8);
            float2 d2 = *(const float2*)(rp + 12);
            float r[14];
            r[0]=a.x;  r[1]=a.y;  r[2]=a.z;  r[3]=a.w;
            r[4]=b.x;  r[5]=b.y;  r[6]=b.z;  r[7]=b.w;
            r[8]=cc.x; r[9]=cc.y; r[10]=cc.z; r[11]=cc.w;
            r[12]=d2.x; r[13]=d2.y;
#pragma unroll
            for (int kw = 0; kw < 7; kw++)
#pragma unroll
                for (int j = 0; j < 8; j++)
                    acc7[j] = fmaf(wv[kh * 7 + kw], r[j + kw], acc7[j]);
        }
    }

    // ---- 3x3x3 depthwise ----
    float wv3[27];
#pragma unroll
    for (int i = 0; i < 27; i++) wv3[i] = wl3[i];
#pragma unroll
    for (int k3 = 0; k3 < 3; k3++) {
        const float* pl = &tile[((ttd + 2 + k3) * LDS_H + (tth + 2)) * PITCH + wloc];
#pragma unroll
        for (int kh = 0; kh < 3; kh++) {
            const float* rp = pl + kh * PITCH;
            float4 a  = *(const float4*)(rp);
            float4 b  = *(const float4*)(rp + 4);
            float4 cc = *(const float4*)(rp + 8);
            float r[12];
            r[0]=a.x;  r[1]=a.y;  r[2]=a.z;  r[3]=a.w;
            r[4]=b.x;  r[5]=b.y;  r[6]=b.z;  r[7]=b.w;
            r[8]=cc.x; r[9]=cc.y; r[10]=cc.z; r[11]=cc.w;
#pragma unroll
            for (int kw = 0; kw < 3; kw++)
#pragma unroll
                for (int j = 0; j < 8; j++)
                    acc3[j] = fmaf(wv3[(k3 * 3 + kh) * 3 + kw], r[j + 2 + kw], acc3[j]);
        }
    }

    // ---- center values (for 1x1x1 branch + residual) ----
    {
        const float* rp = &tile[((ttd + 3) * LDS_H + (tth + 3)) * PITCH + wloc];
        float4 a  = *(const float4*)(rp);
        float4 b  = *(const float4*)(rp + 4);
        float4 cc = *(const float4*)(rp + 8);
        float r[12];
        r[0]=a.x;  r[1]=a.y;  r[2]=a.z;  r[3]=a.w;
        r[4]=b.x;  r[5]=b.y;  r[6]=b.z;  r[7]=b.w;
        r[8]=cc.x; r[9]=cc.y; r[10]=cc.z; r[11]=cc.w;

        const float eps = 1e-5f;
        const float iv7 = g7[c] / sqrtf(v7[c] + eps);
        const float bb7 = b7[c] - m7[c] * iv7;
        const float iv3 = g3[c] / sqrtf(v3[c] + eps);
        const float bb3 = b3[c] - m3[c] * iv3;
        const float iv1 = g1[c] / sqrtf(v1[c] + eps);
        const float bb1 = b1[c] - m1[c] * iv1;
        const float w1c = w1[c];

        float o[8];
#pragma unroll
        for (int j = 0; j < 8; j++) {
            float xv = r[3 + j];
            float y7 = fmaxf(acc7[j] * iv7 + bb7, 0.f);
            float y3 = fmaxf(acc3[j] * iv3 + bb3, 0.f);
            float y1 = fmaxf(xv * w1c * iv1 + bb1, 0.f);
            o[j] = fmaxf(xv + y7 + y3 + y1, 0.f);
        }

        float* op = out + (size_t)(n * C_ + c) * (D_ * H_ * W_)
                  + (size_t)(d0 + ttd) * (H_ * W_) + (h0 + tth) * W_ + (w0 + wloc);
        float4 o0 = make_float4(o[0], o[1], o[2], o[3]);
        float4 o1 = make_float4(o[4], o[5], o[6], o[7]);
        *(float4*)(op)     = o0;
        *(float4*)(op + 4) = o1;
    }
}

extern "C" void kernel_launch(void* const* d_in, const int* in_sizes, int n_in,
                              void* d_out, int out_size, void* d_ws, size_t ws_size,
                              hipStream_t stream) {
    const float* x  = (const float*)d_in[0];
    const float* w7 = (const float*)d_in[1];
    const float* w3 = (const float*)d_in[2];
    const float* w1 = (const float*)d_in[3];
    const float* g7 = (const float*)d_in[4];
    const float* b7 = (const float*)d_in[5];
    const float* m7 = (const float*)d_in[6];
    const float* v7 = (const float*)d_in[7];
    const float* g3 = (const float*)d_in[8];
    const float* b3 = (const float*)d_in[9];
    const float* m3 = (const float*)d_in[10];
    const float* v3 = (const float*)d_in[11];
    const float* g1 = (const float*)d_in[12];
    const float* b1 = (const float*)d_in[13];
    const float* m1 = (const float*)d_in[14];
    const float* v1 = (const float*)d_in[15];
    float* out = (float*)d_out;

    dim3 grid(512, 64);   // 512 tiles per slab x 64 (n,c) slabs
    dim3 block(256);
    hipLaunchKernelGGL(replk3d_kernel, grid, block, 0, stream,
                       x, w7, w3, w1, g7, b7, m7, v7, g3, b3, m3, v3,
                       g1, b1, m1, v1, out);
}

// Round 3
// 1067.042 us; speedup vs baseline: 1.0395x; 1.0395x over previous
//
#include <hip/hip_runtime.h>

#define D_ 64
#define H_ 128
#define W_ 128
#define C_ 32

// block tile (outputs): 8d x 16h x 32w = 4096 outputs, 16 per thread (2h x 8w)
#define TD 8
#define TH 16
#define TW 32
// LDS tile with halo 3 each side
#define LDS_D 14
#define LDS_H 22
#define LDS_W 38
#define PITCH 48   // 12 quads of 16B; quad-XOR swizzled

__global__ __launch_bounds__(256, 2) void replk3d_kernel(
    const float* __restrict__ x,
    const float* __restrict__ w7, const float* __restrict__ w3, const float* __restrict__ w1,
    const float* __restrict__ g7, const float* __restrict__ b7, const float* __restrict__ m7, const float* __restrict__ v7,
    const float* __restrict__ g3, const float* __restrict__ b3, const float* __restrict__ m3, const float* __restrict__ v3,
    const float* __restrict__ g1, const float* __restrict__ b1, const float* __restrict__ m1, const float* __restrict__ v1,
    float* __restrict__ out)
{
    __shared__ __align__(16) float tile[LDS_D * LDS_H * PITCH]; // 14*22*48*4 = 59.1 KB
    __shared__ __align__(16) float wl7[7 * 52];
    __shared__ __align__(16) float wl3[28];

    const int bx = blockIdx.x;        // 256 tiles per slab: 4w x 8h x 8d
    const int slab = blockIdx.y;      // 64 slabs
    const int c = slab & 31;
    const int n = slab >> 5;
    const int w0 = (bx & 3) * TW;
    const int h0 = ((bx >> 2) & 7) * TH;
    const int d0 = (bx >> 5) * TD;
    const int tid = threadIdx.x;

    // ---- stage weights ----
    for (int s = tid; s < 343; s += 256)
        wl7[(s / 49) * 52 + (s % 49)] = w7[c * 343 + s];
    if (tid < 27)
        wl3[tid] = w3[c * 27 + tid];

    // ---- stage input tile (zero halo), quad-XOR swizzled ----
    const float* xc = x + (size_t)(n * C_ + c) * (D_ * H_ * W_);
    for (int s = tid; s < LDS_D * LDS_H * LDS_W; s += 256) {
        int ww = s % LDS_W;
        int t  = s / LDS_W;
        int hh = t % LDS_H;
        int dd = t / LDS_H;
        int gd = d0 - 3 + dd, gh = h0 - 3 + hh, gw = w0 - 3 + ww;
        float v = 0.f;
        if ((unsigned)gd < (unsigned)D_ && (unsigned)gh < (unsigned)H_ && (unsigned)gw < (unsigned)W_)
            v = xc[(size_t)gd * (H_ * W_) + gh * W_ + gw];
        int rowlin = dd * LDS_H + hh;
        int k2 = (rowlin >> 1) & 3;
        tile[rowlin * PITCH + ((((ww >> 2) ^ k2)) << 2) + (ww & 3)] = v;
    }
    __syncthreads();

    // thread -> outputs: 2 h rows x 8 consecutive w
    const int ttw = tid & 3;          // 4 w-groups of 8
    const int tth = (tid >> 2) & 7;   // 8 h-groups of 2
    const int ttd = tid >> 5;         // 8 d
    const int hb = tth * 2;
    const int wq = 2 * ttw;           // base quad of this thread's 16-float window
    const int wloc = ttw * 8;

    float acc7[2][8], acc3[2][8];
#pragma unroll
    for (int j = 0; j < 8; j++) {
        acc7[0][j] = 0.f; acc7[1][j] = 0.f;
        acc3[0][j] = 0.f; acc3[1][j] = 0.f;
    }

    // ---- 7x7x7 depthwise, register row-reuse across the 2 h-outputs ----
#pragma unroll 1
    for (int kd = 0; kd < 7; kd++) {
        float wv[49];
#pragma unroll
        for (int i = 0; i < 12; i++) {
            float4 t4 = *(const float4*)&wl7[kd * 52 + i * 4];
            wv[i * 4 + 0] = t4.x; wv[i * 4 + 1] = t4.y;
            wv[i * 4 + 2] = t4.z; wv[i * 4 + 3] = t4.w;
        }
        wv[48] = wl7[kd * 52 + 48];
        const int ddl = ttd + kd;
#pragma unroll
        for (int rr = 0; rr < 8; rr++) {
            const int rowlin = ddl * LDS_H + hb + rr;
            const int k2 = (rowlin >> 1) & 3;
            const float* rp = &tile[rowlin * PITCH];
            float4 A  = *(const float4*)&rp[((wq + 0) ^ k2) << 2];
            float4 B  = *(const float4*)&rp[((wq + 1) ^ k2) << 2];
            float4 Cq = *(const float4*)&rp[((wq + 2) ^ k2) << 2];
            float4 Dq = *(const float4*)&rp[((wq + 3) ^ k2) << 2];
            float r[16];
            r[0]=A.x;  r[1]=A.y;  r[2]=A.z;  r[3]=A.w;
            r[4]=B.x;  r[5]=B.y;  r[6]=B.z;  r[7]=B.w;
            r[8]=Cq.x; r[9]=Cq.y; r[10]=Cq.z; r[11]=Cq.w;
            r[12]=Dq.x; r[13]=Dq.y; r[14]=Dq.z; r[15]=Dq.w;
            if (rr <= 6) {   // contributes kh=rr to h-output 0
#pragma unroll
                for (int kw = 0; kw < 7; kw++)
#pragma unroll
                    for (int j = 0; j < 8; j++)
                        acc7[0][j] = fmaf(wv[rr * 7 + kw], r[j + kw], acc7[0][j]);
            }
            if (rr >= 1) {   // contributes kh=rr-1 to h-output 1
#pragma unroll
                for (int kw = 0; kw < 7; kw++)
#pragma unroll
                    for (int j = 0; j < 8; j++)
                        acc7[1][j] = fmaf(wv[(rr - 1) * 7 + kw], r[j + kw], acc7[1][j]);
            }
        }
    }

    // ---- 3x3x3 depthwise ----
    {
        float wv3[27];
#pragma unroll
        for (int i = 0; i < 6; i++) {
            float4 t4 = *(const float4*)&wl3[i * 4];
            wv3[i * 4 + 0] = t4.x; wv3[i * 4 + 1] = t4.y;
            wv3[i * 4 + 2] = t4.z; wv3[i * 4 + 3] = t4.w;
        }
        wv3[24] = wl3[24]; wv3[25] = wl3[25]; wv3[26] = wl3[26];
#pragma unroll
        for (int kd3 = 0; kd3 < 3; kd3++) {
            const int ddl = ttd + 2 + kd3;
#pragma unroll
            for (int rr = 0; rr < 4; rr++) {
                const int rowlin = ddl * LDS_H + hb + 2 + rr;
                const int k2 = (rowlin >> 1) & 3;
                const float* rp = &tile[rowlin * PITCH];
                float4 A  = *(const float4*)&rp[((wq + 0) ^ k2) << 2];
                float4 B  = *(const float4*)&rp[((wq + 1) ^ k2) << 2];
                float4 Cq = *(const float4*)&rp[((wq + 2) ^ k2) << 2];
                float r[12];
                r[0]=A.x;  r[1]=A.y;  r[2]=A.z;  r[3]=A.w;
                r[4]=B.x;  r[5]=B.y;  r[6]=B.z;  r[7]=B.w;
                r[8]=Cq.x; r[9]=Cq.y; r[10]=Cq.z; r[11]=Cq.w;
                if (rr <= 2) {
#pragma unroll
                    for (int kw = 0; kw < 3; kw++)
#pragma unroll
                        for (int j = 0; j < 8; j++)
                            acc3[0][j] = fmaf(wv3[(kd3 * 3 + rr) * 3 + kw], r[2 + j + kw], acc3[0][j]);
                }
                if (rr >= 1) {
#pragma unroll
                    for (int kw = 0; kw < 3; kw++)
#pragma unroll
                        for (int j = 0; j < 8; j++)
                            acc3[1][j] = fmaf(wv3[(kd3 * 3 + rr - 1) * 3 + kw], r[2 + j + kw], acc3[1][j]);
                }
            }
        }
    }

    // ---- epilogue: BN+ReLU per branch, 1x1x1 branch, residual ----
    const float eps = 1e-5f;
    const float iv7 = g7[c] / sqrtf(v7[c] + eps);
    const float bb7 = b7[c] - m7[c] * iv7;
    const float iv3 = g3[c] / sqrtf(v3[c] + eps);
    const float bb3 = b3[c] - m3[c] * iv3;
    const float iv1 = g1[c] / sqrtf(v1[c] + eps);
    const float bb1 = b1[c] - m1[c] * iv1;
    const float s1  = w1[c] * iv1;

#pragma unroll
    for (int ho = 0; ho < 2; ho++) {
        const int rowlin = (ttd + 3) * LDS_H + hb + 3 + ho;
        const int k2 = (rowlin >> 1) & 3;
        const float* rp = &tile[rowlin * PITCH];
        float4 A  = *(const float4*)&rp[((wq + 0) ^ k2) << 2];
        float4 B  = *(const float4*)&rp[((wq + 1) ^ k2) << 2];
        float4 Cq = *(const float4*)&rp[((wq + 2) ^ k2) << 2];
        float r[12];
        r[0]=A.x;  r[1]=A.y;  r[2]=A.z;  r[3]=A.w;
        r[4]=B.x;  r[5]=B.y;  r[6]=B.z;  r[7]=B.w;
        r[8]=Cq.x; r[9]=Cq.y; r[10]=Cq.z; r[11]=Cq.w;

        float o[8];
#pragma unroll
        for (int j = 0; j < 8; j++) {
            float xv = r[3 + j];
            float y7 = fmaxf(fmaf(acc7[ho][j], iv7, bb7), 0.f);
            float y3 = fmaxf(fmaf(acc3[ho][j], iv3, bb3), 0.f);
            float y1 = fmaxf(fmaf(xv, s1, bb1), 0.f);
            o[j] = fmaxf(xv + y7 + y3 + y1, 0.f);
        }

        float* op = out + ((size_t)(n * C_ + c) * D_ + (d0 + ttd)) * (H_ * W_)
                  + (size_t)(h0 + hb + ho) * W_ + w0 + wloc;
        *(float4*)(op)     = make_float4(o[0], o[1], o[2], o[3]);
        *(float4*)(op + 4) = make_float4(o[4], o[5], o[6], o[7]);
    }
}

extern "C" void kernel_launch(void* const* d_in, const int* in_sizes, int n_in,
                              void* d_out, int out_size, void* d_ws, size_t ws_size,
                              hipStream_t stream) {
    const float* x  = (const float*)d_in[0];
    const float* w7 = (const float*)d_in[1];
    const float* w3 = (const float*)d_in[2];
    const float* w1 = (const float*)d_in[3];
    const float* g7 = (const float*)d_in[4];
    const float* b7 = (const float*)d_in[5];
    const float* m7 = (const float*)d_in[6];
    const float* v7 = (const float*)d_in[7];
    const float* g3 = (const float*)d_in[8];
    const float* b3 = (const float*)d_in[9];
    const float* m3 = (const float*)d_in[10];
    const float* v3 = (const float*)d_in[11];
    const float* g1 = (const float*)d_in[12];
    const float* b1 = (const float*)d_in[13];
    const float* m1 = (const float*)d_in[14];
    const float* v1 = (const float*)d_in[15];
    float* out = (float*)d_out;

    dim3 grid(256, 64);   // 4w x 8h x 8d tiles  x  64 (n,c) slabs
    dim3 block(256);
    hipLaunchKernelGGL(replk3d_kernel, grid, block, 0, stream,
                       x, w7, w3, w1, g7, b7, m7, v7, g3, b3, m3, v3,
                       g1, b1, m1, v1, out);
}

// Round 4
// 679.837 us; speedup vs baseline: 1.6316x; 1.5696x over previous
//
#include <hip/hip_runtime.h>

#define Dd 64
#define Hh 128
#define Ww 128
#define Cc 32

// block tile: 32d x 16h x 16w outputs; wave = 8d x 16h x 16w
#define BD 32
#define BH 16
#define BW 16
#define ZR (BD + 6)        // 38 staged z-rows
#define HR (BH + 6)        // 22 staged h-rows
#define NR (ZR * HR)       // 836 (z,h) rows, 32 bf16 cols each
#define ROWS8 (NR * 4)     // 3344 16B-blocks to stage

typedef __attribute__((ext_vector_type(8))) short short8;   // 8 bf16 (4 VGPR)
typedef __attribute__((ext_vector_type(4))) float floatx4;  // MFMA acc

static __device__ __forceinline__ unsigned short f2bf(float f) {
    unsigned u = __builtin_bit_cast(unsigned, f);
    u += 0x7fffu + ((u >> 16) & 1u);   // RNE
    return (unsigned short)(u >> 16);
}

// Build an A-fragment (8 bf16 window from zero-padded weight array) starting
// at element idx0; handles odd/even alignment via 5 aligned b32 reads.
static __device__ __forceinline__ short8 buildfrag(const unsigned short* base, int idx0) {
    const unsigned* wp = (const unsigned*)base;
    int w0i = idx0 >> 1;
    unsigned W0 = wp[w0i], W1 = wp[w0i + 1], W2 = wp[w0i + 2], W3 = wp[w0i + 3], W4 = wp[w0i + 4];
    unsigned e0, e1, e2, e3;
    if (idx0 & 1) {
        e0 = (W0 >> 16) | (W1 << 16);
        e1 = (W1 >> 16) | (W2 << 16);
        e2 = (W2 >> 16) | (W3 << 16);
        e3 = (W3 >> 16) | (W4 << 16);
    } else {
        e0 = W0; e1 = W1; e2 = W2; e3 = W3;
    }
    union { unsigned u[4]; short8 s; } cv;
    cv.u[0] = e0; cv.u[1] = e1; cv.u[2] = e2; cv.u[3] = e3;
    return cv.s;
}

__global__ __launch_bounds__(256, 1) void replk_mfma(
    const float* __restrict__ x,
    const float* __restrict__ w7, const float* __restrict__ w3, const float* __restrict__ w1,
    const float* __restrict__ g7, const float* __restrict__ b7, const float* __restrict__ m7, const float* __restrict__ v7,
    const float* __restrict__ g3, const float* __restrict__ b3, const float* __restrict__ m3, const float* __restrict__ v3,
    const float* __restrict__ g1, const float* __restrict__ b1, const float* __restrict__ m1, const float* __restrict__ v1,
    float* __restrict__ out)
{
    __shared__ __align__(16) unsigned short tile[NR * 32];   // 53.5 KB bf16, swizzled 16B blocks
    __shared__ __align__(16) unsigned short wpad[58 * 48];   // 5.4 KB padded weight windows

    const int tid = threadIdx.x;
    const int bx = blockIdx.x;          // 128 = 8 wblk x 8 hblk x 2 dblk
    const int slab = blockIdx.y;        // 64 = (n,c)
    const int c = slab & 31;
    const int nb = slab >> 5;
    const int w0 = (bx & 7) * BW;
    const int h0 = ((bx >> 3) & 7) * BH;
    const int d0 = (bx >> 6) * BD;

    const float* xc = x + (size_t)(nb * Cc + c) * (Dd * Hh * Ww);

    // ---- stage zero-padded bf16 weight windows (58 planes x 48) ----
    // plane<49: 7^3 (kd*7+kh), band value at i-15 in [0,7)
    // plane>=49: 3^3 (kd3*3+kh3), band value at i-17 in [0,3)
    for (int e = tid; e < 58 * 48; e += 256) {
        int pl = e / 48, i = e - pl * 48;
        unsigned short v = 0;
        if (pl < 49) {
            int kv = i - 15;
            if (kv >= 0 && kv < 7)
                v = f2bf(w7[c * 343 + (pl / 7) * 49 + (pl % 7) * 7 + kv]);
        } else {
            int p3 = pl - 49;
            int kv = i - 17;
            if (kv >= 0 && kv < 3)
                v = f2bf(w3[c * 27 + (p3 / 3) * 9 + (p3 % 3) * 3 + kv]);
        }
        wpad[e] = v;
    }

    // ---- stage input tile fp32 -> bf16, 16B-block swizzle S(R)=(R+(R>>2))&3 ----
    for (int it = 0; it < 14; it++) {
        int s8 = tid + it * 256;
        if (s8 < ROWS8) {
            int R = s8 >> 2, bl = s8 & 3;
            int zi = R / HR, hr = R - zi * HR;
            int gz = d0 - 3 + zi, gh = h0 - 3 + hr, gw0 = w0 - 3 + bl * 8;
            float v[8];
#pragma unroll
            for (int j = 0; j < 8; j++) v[j] = 0.f;
            if ((unsigned)gz < (unsigned)Dd && (unsigned)gh < (unsigned)Hh) {
                const float* src = xc + ((size_t)gz * Hh + gh) * Ww + gw0;
                if (gw0 >= 0 && gw0 + 8 <= Ww) {
                    float4 a = *(const float4*)src;
                    float4 b = *(const float4*)(src + 4);
                    v[0] = a.x; v[1] = a.y; v[2] = a.z; v[3] = a.w;
                    v[4] = b.x; v[5] = b.y; v[6] = b.z; v[7] = b.w;
                } else {
#pragma unroll
                    for (int j = 0; j < 8; j++) {
                        int gw = gw0 + j;
                        if ((unsigned)gw < (unsigned)Ww) v[j] = src[j];
                    }
                }
            }
            int S = (R + (R >> 2)) & 3;
            unsigned short* dst = &tile[R * 32 + ((bl ^ S) << 3)];
            uint4 pk;
            pk.x = (unsigned)f2bf(v[0]) | ((unsigned)f2bf(v[1]) << 16);
            pk.y = (unsigned)f2bf(v[2]) | ((unsigned)f2bf(v[3]) << 16);
            pk.z = (unsigned)f2bf(v[4]) | ((unsigned)f2bf(v[5]) << 16);
            pk.w = (unsigned)f2bf(v[6]) | ((unsigned)f2bf(v[7]) << 16);
            *(uint4*)dst = pk;
        }
    }

    // BN constants (wave-uniform scalar loads)
    const float eps = 1e-5f;
    const float iv7 = g7[c] / sqrtf(v7[c] + eps);
    const float bb7 = b7[c] - m7[c] * iv7;
    const float iv3 = g3[c] / sqrtf(v3[c] + eps);
    const float bb3 = b3[c] - m3[c] * iv3;
    const float iv1 = g1[c] / sqrtf(v1[c] + eps);
    const float bb1 = b1[c] - m1[c] * iv1;
    const float s1 = w1[c] * iv1;

    __syncthreads();

    const int lane = tid & 63;
    const int wave = tid >> 6;
    const int q = lane & 15;        // n (h-row) for B/C/D; m for A build
    const int p = lane >> 4;        // k-group
    const int zbase = wave * 8;     // wave owns d-outputs [zbase, zbase+8)

    // ---- build A fragments in registers ----
    // A7[m][k] = wt7[kd][kh][k-m] (k-m in [0,7));  idx0 = (8p - q) + 15
    // A3[m][k] = wt3[kd][kh][k-m-2] (in [0,3));    idx0 = (8p - q - 2) + 17 = same
    const int idx0 = 8 * p - q + 15;
    short8 A7[49];
    short8 A3[9];
#pragma unroll
    for (int pl = 0; pl < 49; pl++) A7[pl] = buildfrag(&wpad[pl * 48], idx0);
#pragma unroll
    for (int pl = 0; pl < 9; pl++)  A3[pl] = buildfrag(&wpad[(49 + pl) * 48], idx0);

    floatx4 acc7[8], acc3[8];
#pragma unroll
    for (int i = 0; i < 8; i++) { acc7[i] = (floatx4)0.f; acc3[i] = (floatx4)0.f; }

    // ---- main loop: one zi-plane of B rows feeds all matching (kd,dd) ----
#pragma unroll
    for (int zi = 0; zi < 14; zi++) {
        short8 B[7];
#pragma unroll
        for (int kh = 0; kh < 7; kh++) {
            int R = (zbase + zi) * HR + q + kh;
            int S = (R + (R >> 2)) & 3;
            B[kh] = *(const short8*)&tile[R * 32 + ((p ^ S) << 3)];
        }
#pragma unroll
        for (int kd = 0; kd < 7; kd++) {
            int dd = zi - kd;
            if (dd >= 0 && dd < 8) {
#pragma unroll
                for (int kh = 0; kh < 7; kh++)
                    acc7[dd] = __builtin_amdgcn_mfma_f32_16x16x32_bf16(
                        A7[kd * 7 + kh], B[kh], acc7[dd], 0, 0, 0);
            }
        }
#pragma unroll
        for (int kd = 0; kd < 3; kd++) {
            int dd = zi - 2 - kd;
            if (dd >= 0 && dd < 8) {
#pragma unroll
                for (int kh = 0; kh < 3; kh++)
                    acc3[dd] = __builtin_amdgcn_mfma_f32_16x16x32_bf16(
                        A3[kd * 3 + kh], B[kh + 2], acc3[dd], 0, 0, 0);
            }
        }
    }

    // ---- epilogue: C/D layout n(col)=lane&15, m(row)=(lane>>4)*4+reg ----
    // output coords: h = h0 + q, w = w0 + p*4 + r, d = d0 + zbase + dd
#pragma unroll
    for (int dd = 0; dd < 8; dd++) {
        int d = d0 + zbase + dd;
        size_t off = ((size_t)(nb * Cc + c) * Dd + d) * (Hh * Ww)
                   + (size_t)(h0 + q) * Ww + w0 + p * 4;
        float4 xv = *(const float4*)(x + off);
        float o[4];
        float xr[4] = { xv.x, xv.y, xv.z, xv.w };
#pragma unroll
        for (int r = 0; r < 4; r++) {
            float y7 = fmaxf(fmaf(acc7[dd][r], iv7, bb7), 0.f);
            float y3 = fmaxf(fmaf(acc3[dd][r], iv3, bb3), 0.f);
            float y1 = fmaxf(fmaf(xr[r], s1, bb1), 0.f);
            o[r] = fmaxf(xr[r] + y7 + y3 + y1, 0.f);
        }
        *(float4*)(out + off) = make_float4(o[0], o[1], o[2], o[3]);
    }
}

extern "C" void kernel_launch(void* const* d_in, const int* in_sizes, int n_in,
                              void* d_out, int out_size, void* d_ws, size_t ws_size,
                              hipStream_t stream) {
    const float* x  = (const float*)d_in[0];
    const float* w7 = (const float*)d_in[1];
    const float* w3 = (const float*)d_in[2];
    const float* w1 = (const float*)d_in[3];
    const float* g7 = (const float*)d_in[4];
    const float* b7 = (const float*)d_in[5];
    const float* m7 = (const float*)d_in[6];
    const float* v7 = (const float*)d_in[7];
    const float* g3 = (const float*)d_in[8];
    const float* b3 = (const float*)d_in[9];
    const float* m3 = (const float*)d_in[10];
    const float* v3 = (const float*)d_in[11];
    const float* g1 = (const float*)d_in[12];
    const float* b1 = (const float*)d_in[13];
    const float* m1 = (const float*)d_in[14];
    const float* v1 = (const float*)d_in[15];
    float* out = (float*)d_out;

    dim3 grid(128, 64);   // (8 wblk x 8 hblk x 2 dblk) x (n,c)
    dim3 block(256);
    hipLaunchKernelGGL(replk_mfma, grid, block, 0, stream,
                       x, w7, w3, w1, g7, b7, m7, v7, g3, b3, m3, v3,
                       g1, b1, m1, v1, out);
}

// Round 5
// 446.314 us; speedup vs baseline: 2.4853x; 1.5232x over previous
//
#include <hip/hip_runtime.h>

#define Dd 64
#define Hh 128
#define Ww 128
#define Cc 32

// block tile: 32d x 16h x 16w outputs; wave = 8d x 16h x 16w
#define BD 32
#define BH 16
#define BW 16
#define ZR (BD + 6)        // 38 staged z-rows
#define HR (BH + 6)        // 22 staged h-rows
#define NR (ZR * HR)       // 836 (z,h) rows, 32 bf16 cols each
#define ROWS8 (NR * 4)     // 3344 16B-blocks to stage

typedef __attribute__((ext_vector_type(8))) short short8;   // 8 bf16 (4 VGPR)
typedef __attribute__((ext_vector_type(4))) float floatx4;  // MFMA acc

static __device__ __forceinline__ unsigned short f2bf(float f) {
    unsigned u = __builtin_bit_cast(unsigned, f);
    u += 0x7fffu + ((u >> 16) & 1u);   // RNE
    return (unsigned short)(u >> 16);
}

// Build an A-fragment (8 bf16 window from zero-padded weight array) starting
// at element idx0; handles odd/even alignment via 5 aligned b32 reads.
static __device__ __forceinline__ short8 buildfrag(const unsigned short* base, int idx0) {
    const unsigned* wp = (const unsigned*)base;
    int w0i = idx0 >> 1;
    unsigned W0 = wp[w0i], W1 = wp[w0i + 1], W2 = wp[w0i + 2], W3 = wp[w0i + 3], W4 = wp[w0i + 4];
    unsigned e0, e1, e2, e3;
    if (idx0 & 1) {
        e0 = (W0 >> 16) | (W1 << 16);
        e1 = (W1 >> 16) | (W2 << 16);
        e2 = (W2 >> 16) | (W3 << 16);
        e3 = (W3 >> 16) | (W4 << 16);
    } else {
        e0 = W0; e1 = W1; e2 = W2; e3 = W3;
    }
    union { unsigned u[4]; short8 s; } cv;
    cv.u[0] = e0; cv.u[1] = e1; cv.u[2] = e2; cv.u[3] = e3;
    return cv.s;
}

__global__ __launch_bounds__(256, 2) void replk_mfma(
    const float* __restrict__ x,
    const float* __restrict__ w7, const float* __restrict__ w3, const float* __restrict__ w1,
    const float* __restrict__ g7, const float* __restrict__ b7, const float* __restrict__ m7, const float* __restrict__ v7,
    const float* __restrict__ g3, const float* __restrict__ b3, const float* __restrict__ m3, const float* __restrict__ v3,
    const float* __restrict__ g1, const float* __restrict__ b1, const float* __restrict__ m1, const float* __restrict__ v1,
    float* __restrict__ out)
{
    __shared__ __align__(16) unsigned short tile[NR * 32];   // 53.5 KB bf16, swizzled 16B blocks
    __shared__ __align__(16) unsigned short wpad[58 * 48];   // 5.4 KB padded weight windows

    const int tid = threadIdx.x;
    const int bx = blockIdx.x;          // 128 = 8 wblk x 8 hblk x 2 dblk
    const int slab = blockIdx.y;        // 64 = (n,c)
    const int c = slab & 31;
    const int nb = slab >> 5;
    const int w0 = (bx & 7) * BW;
    const int h0 = ((bx >> 3) & 7) * BH;
    const int d0 = (bx >> 6) * BD;

    const float* xc = x + (size_t)(nb * Cc + c) * (Dd * Hh * Ww);

    // ---- stage zero-padded bf16 weight windows (58 planes x 48) ----
    for (int e = tid; e < 58 * 48; e += 256) {
        int pl = e / 48, i = e - pl * 48;
        unsigned short v = 0;
        if (pl < 49) {
            int kv = i - 15;
            if (kv >= 0 && kv < 7)
                v = f2bf(w7[c * 343 + (pl / 7) * 49 + (pl % 7) * 7 + kv]);
        } else {
            int p3 = pl - 49;
            int kv = i - 17;
            if (kv >= 0 && kv < 3)
                v = f2bf(w3[c * 27 + (p3 / 3) * 9 + (p3 % 3) * 3 + kv]);
        }
        wpad[e] = v;
    }

    // ---- stage input tile fp32 -> bf16, 16B-block swizzle S(R)=(R+(R>>2))&3 ----
    for (int it = 0; it < 14; it++) {
        int s8 = tid + it * 256;
        if (s8 < ROWS8) {
            int R = s8 >> 2, bl = s8 & 3;
            int zi = R / HR, hr = R - zi * HR;
            int gz = d0 - 3 + zi, gh = h0 - 3 + hr, gw0 = w0 - 3 + bl * 8;
            float v[8];
#pragma unroll
            for (int j = 0; j < 8; j++) v[j] = 0.f;
            if ((unsigned)gz < (unsigned)Dd && (unsigned)gh < (unsigned)Hh) {
                const float* src = xc + ((size_t)gz * Hh + gh) * Ww + gw0;
                if (gw0 >= 0 && gw0 + 8 <= Ww) {
                    float4 a = *(const float4*)src;
                    float4 b = *(const float4*)(src + 4);
                    v[0] = a.x; v[1] = a.y; v[2] = a.z; v[3] = a.w;
                    v[4] = b.x; v[5] = b.y; v[6] = b.z; v[7] = b.w;
                } else {
#pragma unroll
                    for (int j = 0; j < 8; j++) {
                        int gw = gw0 + j;
                        if ((unsigned)gw < (unsigned)Ww) v[j] = src[j];
                    }
                }
            }
            int S = (R + (R >> 2)) & 3;
            unsigned short* dst = &tile[R * 32 + ((bl ^ S) << 3)];
            uint4 pk;
            pk.x = (unsigned)f2bf(v[0]) | ((unsigned)f2bf(v[1]) << 16);
            pk.y = (unsigned)f2bf(v[2]) | ((unsigned)f2bf(v[3]) << 16);
            pk.z = (unsigned)f2bf(v[4]) | ((unsigned)f2bf(v[5]) << 16);
            pk.w = (unsigned)f2bf(v[6]) | ((unsigned)f2bf(v[7]) << 16);
            *(uint4*)dst = pk;
        }
    }

    // BN constants (wave-uniform scalar loads)
    const float eps = 1e-5f;
    const float iv7 = g7[c] / sqrtf(v7[c] + eps);
    const float bb7 = b7[c] - m7[c] * iv7;
    const float iv3 = g3[c] / sqrtf(v3[c] + eps);
    const float bb3 = b3[c] - m3[c] * iv3;
    const float iv1 = g1[c] / sqrtf(v1[c] + eps);
    const float bb1 = b1[c] - m1[c] * iv1;
    const float s1 = w1[c] * iv1;

    __syncthreads();

    const int lane = tid & 63;
    const int wave = tid >> 6;
    const int q = lane & 15;        // n (h-row) for B/C/D
    const int p = lane >> 4;        // k-group
    const int zbase = wave * 8;     // wave owns d-outputs [zbase, zbase+8)
    const int idx0 = 8 * p - q + 15;

    floatx4 acc7[8], acc3[8];
#pragma unroll
    for (int i = 0; i < 8; i++) { acc7[i] = (floatx4)0.f; acc3[i] = (floatx4)0.f; }

    // ---- kh-outer main loop: per pass, tiny live A-set (7 + 3 frags),
    //      B row loaded once per zi and shared by up to 10 MFMAs ----
#pragma unroll 1
    for (int kh = 0; kh < 7; kh++) {
        short8 A7k[7];
#pragma unroll
        for (int kd = 0; kd < 7; kd++)
            A7k[kd] = buildfrag(&wpad[(kd * 7 + kh) * 48], idx0);

        const bool has3 = (kh >= 2) && (kh < 5);
        short8 A3k[3];
#pragma unroll
        for (int kd3 = 0; kd3 < 3; kd3++) A3k[kd3] = (short8)0;
        if (has3) {
            const int kh3 = kh - 2;
#pragma unroll
            for (int kd3 = 0; kd3 < 3; kd3++)
                A3k[kd3] = buildfrag(&wpad[(49 + kd3 * 3 + kh3) * 48], idx0);
        }

#pragma unroll
        for (int zi = 0; zi < 14; zi++) {
            const int R = (zbase + zi) * HR + q + kh;
            const int S = (R + (R >> 2)) & 3;
            short8 B = *(const short8*)&tile[R * 32 + ((p ^ S) << 3)];
            // kd descending -> dd ascending: dependent acc updates ~6 apart
#pragma unroll
            for (int kd = 6; kd >= 0; kd--) {
                const int dd = zi - kd;
                if (dd >= 0 && dd < 8)
                    acc7[dd] = __builtin_amdgcn_mfma_f32_16x16x32_bf16(
                        A7k[kd], B, acc7[dd], 0, 0, 0);
            }
            if (has3) {
#pragma unroll
                for (int kd3 = 2; kd3 >= 0; kd3--) {
                    const int dd = zi - 2 - kd3;
                    if (dd >= 0 && dd < 8)
                        acc3[dd] = __builtin_amdgcn_mfma_f32_16x16x32_bf16(
                            A3k[kd3], B, acc3[dd], 0, 0, 0);
                }
            }
        }
    }

    // ---- epilogue: C/D layout col=lane&15, row=(lane>>4)*4+reg ----
    // output coords: h = h0 + q, w = w0 + p*4 + r, d = d0 + zbase + dd
#pragma unroll
    for (int dd = 0; dd < 8; dd++) {
        int d = d0 + zbase + dd;
        size_t off = ((size_t)(nb * Cc + c) * Dd + d) * (Hh * Ww)
                   + (size_t)(h0 + q) * Ww + w0 + p * 4;
        float4 xv = *(const float4*)(x + off);
        float o[4];
        float xr[4] = { xv.x, xv.y, xv.z, xv.w };
#pragma unroll
        for (int r = 0; r < 4; r++) {
            float y7 = fmaxf(fmaf(acc7[dd][r], iv7, bb7), 0.f);
            float y3 = fmaxf(fmaf(acc3[dd][r], iv3, bb3), 0.f);
            float y1 = fmaxf(fmaf(xr[r], s1, bb1), 0.f);
            o[r] = fmaxf(xr[r] + y7 + y3 + y1, 0.f);
        }
        *(float4*)(out + off) = make_float4(o[0], o[1], o[2], o[3]);
    }
}

extern "C" void kernel_launch(void* const* d_in, const int* in_sizes, int n_in,
                              void* d_out, int out_size, void* d_ws, size_t ws_size,
                              hipStream_t stream) {
    const float* x  = (const float*)d_in[0];
    const float* w7 = (const float*)d_in[1];
    const float* w3 = (const float*)d_in[2];
    const float* w1 = (const float*)d_in[3];
    const float* g7 = (const float*)d_in[4];
    const float* b7 = (const float*)d_in[5];
    const float* m7 = (const float*)d_in[6];
    const float* v7 = (const float*)d_in[7];
    const float* g3 = (const float*)d_in[8];
    const float* b3 = (const float*)d_in[9];
    const float* m3 = (const float*)d_in[10];
    const float* v3 = (const float*)d_in[11];
    const float* g1 = (const float*)d_in[12];
    const float* b1 = (const float*)d_in[13];
    const float* m1 = (const float*)d_in[14];
    const float* v1 = (const float*)d_in[15];
    float* out = (float*)d_out;

    dim3 grid(128, 64);   // (8 wblk x 8 hblk x 2 dblk) x (n,c)
    dim3 block(256);
    hipLaunchKernelGGL(replk_mfma, grid, block, 0, stream,
                       x, w7, w3, w1, g7, b7, m7, v7, g3, b3, m3, v3,
                       g1, b1, m1, v1, out);
}

// Round 7
// 327.104 us; speedup vs baseline: 3.3910x; 1.3644x over previous
//
#include <hip/hip_runtime.h>

#define Dd 64
#define Hh 128
#define Ww 128
#define Cc 32

// block tile: 32d x 16h x 16w outputs; wave = 8d x 16h x 16w
#define BD 32
#define BH 16
#define BW 16
#define ZR (BD + 6)        // 38 staged z-planes
#define HR (BH + 6)        // 22 staged h-rows
#define NR (ZR * HR)       // 836 (z,h) rows
#define RCOLS 24           // bf16 cols per row (22 needed; 24 => three 16B blocks)
#define BLKROW 3
#define NBLK (NR * BLKROW) // 2508 16B blocks to stage

typedef __attribute__((ext_vector_type(8))) short short8;   // 8 bf16 (4 VGPR)
typedef __attribute__((ext_vector_type(4))) float floatx4;  // MFMA acc

static __device__ __forceinline__ unsigned short f2bf(float f) {
    unsigned u = __builtin_bit_cast(unsigned, f);
    u += 0x7fffu + ((u >> 16) & 1u);   // RNE
    return (unsigned short)(u >> 16);
}

// Build an A-fragment (8 bf16 window from zero-padded weight plane) starting
// at element idx0; handles odd/even alignment via 5 aligned b32 reads.
static __device__ __forceinline__ short8 buildfrag(const unsigned short* base, int idx0) {
    const unsigned* wp = (const unsigned*)base;
    int w0i = idx0 >> 1;
    unsigned W0 = wp[w0i], W1 = wp[w0i + 1], W2 = wp[w0i + 2], W3 = wp[w0i + 3], W4 = wp[w0i + 4];
    unsigned e0, e1, e2, e3;
    if (idx0 & 1) {
        e0 = (W0 >> 16) | (W1 << 16);
        e1 = (W1 >> 16) | (W2 << 16);
        e2 = (W2 >> 16) | (W3 << 16);
        e3 = (W3 >> 16) | (W4 << 16);
    } else {
        e0 = W0; e1 = W1; e2 = W2; e3 = W3;
    }
    union { unsigned u[4]; short8 s; } cv;
    cv.u[0] = e0; cv.u[1] = e1; cv.u[2] = e2; cv.u[3] = e3;
    return cv.s;
}

// Single kernel: no cross-kernel d_ws producer/consumer (round-6 post-timing
// failure was the graph-replayed build_atab->main dependency reading poison).
__global__ __launch_bounds__(256, 3) void replk_mfma(
    const float* __restrict__ x,
    const float* __restrict__ w7, const float* __restrict__ w3, const float* __restrict__ w1,
    const float* __restrict__ g7, const float* __restrict__ b7, const float* __restrict__ m7, const float* __restrict__ v7,
    const float* __restrict__ g3, const float* __restrict__ b3, const float* __restrict__ m3, const float* __restrict__ v3,
    const float* __restrict__ g1, const float* __restrict__ b1, const float* __restrict__ m1, const float* __restrict__ v1,
    float* __restrict__ out)
{
    __shared__ __align__(16) unsigned short tile[NR * RCOLS];  // 40.1 KB; 48B pitch
    __shared__ __align__(16) unsigned short wpad[58 * 48];     // 5.4 KB padded weight windows

    const int tid = threadIdx.x;
    const int bx = blockIdx.x;          // 128 = 8 wblk x 8 hblk x 2 dblk
    const int slab = blockIdx.y;        // 64 = (n,c)
    const int c = slab & 31;
    const int nb = slab >> 5;
    const int w0 = (bx & 7) * BW;
    const int h0 = ((bx >> 3) & 7) * BH;
    const int d0 = (bx >> 6) * BD;

    const float* xc = x + (size_t)(nb * Cc + c) * (Dd * Hh * Ww);

    // ---- stage zero-padded bf16 weight windows (58 planes x 48) ----
    // plane<49: 7^3 (kd*7+kh), band value at i-15 in [0,7)
    // plane>=49: 3^3 (kd3*3+kh3), band value at i-17 in [0,3)
    for (int e = tid; e < 58 * 48; e += 256) {
        int pl = e / 48, i = e - pl * 48;
        unsigned short v = 0;
        if (pl < 49) {
            int kv = i - 15;
            if (kv >= 0 && kv < 7)
                v = f2bf(w7[c * 343 + (pl / 7) * 49 + (pl % 7) * 7 + kv]);
        } else {
            int p3 = pl - 49;
            int kv = i - 17;
            if (kv >= 0 && kv < 3)
                v = f2bf(w3[c * 27 + (p3 / 3) * 9 + (p3 % 3) * 3 + kv]);
        }
        wpad[e] = v;
    }

    // ---- stage input tile fp32 -> bf16, 24 cols/row, linear (no swizzle) ----
#pragma unroll
    for (int it = 0; it < 10; it++) {
        int s = tid + it * 256;
        if (s < NBLK) {
            int R = s / BLKROW, bl = s - R * BLKROW;
            int zi = R / HR, hr = R - zi * HR;
            int gz = d0 - 3 + zi, gh = h0 - 3 + hr, gw0 = w0 - 3 + bl * 8;
            float v[8];
#pragma unroll
            for (int j = 0; j < 8; j++) v[j] = 0.f;
            if ((unsigned)gz < (unsigned)Dd && (unsigned)gh < (unsigned)Hh) {
                const float* src = xc + ((size_t)gz * Hh + gh) * Ww + gw0;
                if (gw0 >= 0 && gw0 + 8 <= Ww) {
                    float4 a = *(const float4*)src;
                    float4 b = *(const float4*)(src + 4);
                    v[0] = a.x; v[1] = a.y; v[2] = a.z; v[3] = a.w;
                    v[4] = b.x; v[5] = b.y; v[6] = b.z; v[7] = b.w;
                } else {
#pragma unroll
                    for (int j = 0; j < 8; j++) {
                        int gw = gw0 + j;
                        if ((unsigned)gw < (unsigned)Ww) v[j] = src[j];
                    }
                }
            }
            uint4 pk;
            pk.x = (unsigned)f2bf(v[0]) | ((unsigned)f2bf(v[1]) << 16);
            pk.y = (unsigned)f2bf(v[2]) | ((unsigned)f2bf(v[3]) << 16);
            pk.z = (unsigned)f2bf(v[4]) | ((unsigned)f2bf(v[5]) << 16);
            pk.w = (unsigned)f2bf(v[6]) | ((unsigned)f2bf(v[7]) << 16);
            *(uint4*)&tile[R * RCOLS + bl * 8] = pk;
        }
    }

    // BN constants (wave-uniform)
    const float eps = 1e-5f;
    const float iv7 = g7[c] / sqrtf(v7[c] + eps);
    const float bb7 = b7[c] - m7[c] * iv7;
    const float iv3 = g3[c] / sqrtf(v3[c] + eps);
    const float bb3 = b3[c] - m3[c] * iv3;
    const float iv1 = g1[c] / sqrtf(v1[c] + eps);
    const float bb1 = b1[c] - m1[c] * iv1;
    const float s1 = w1[c] * iv1;

    __syncthreads();

    const int lane = tid & 63;
    const int wave = tid >> 6;
    const int q = lane & 15;          // n (h-row) for B; m for A
    const int p = lane >> 4;          // k-group
    const int cg = (p == 3) ? 0 : p;  // p=3's A is all-zero (band ends at k=21);
                                      // alias its B read to cg=0 (broadcast, free)
    const int zbase = wave * 8;       // wave owns d-outputs [zbase, zbase+8)
    const int idx0 = 8 * p - q + 15;

    floatx4 acc7[8], acc3[8];
#pragma unroll
    for (int i = 0; i < 8; i++) { acc7[i] = (floatx4)0.f; acc3[i] = (floatx4)0.f; }

    // ---- kh-outer main loop: 10 A-frags live, B row loaded once per zi ----
#pragma unroll 1
    for (int kh = 0; kh < 7; kh++) {
        short8 A7k[7];
#pragma unroll
        for (int kd = 0; kd < 7; kd++)
            A7k[kd] = buildfrag(&wpad[(kd * 7 + kh) * 48], idx0);

        const bool has3 = (kh >= 2) && (kh < 5);
        short8 A3k[3] = {};
        if (has3) {
            const int kh3 = kh - 2;
#pragma unroll
            for (int kd3 = 0; kd3 < 3; kd3++)
                A3k[kd3] = buildfrag(&wpad[(49 + kd3 * 3 + kh3) * 48], idx0);
        }

#pragma unroll
        for (int zi = 0; zi < 14; zi++) {
            const int R = (zbase + zi) * HR + q + kh;
            short8 B = *(const short8*)&tile[R * RCOLS + cg * 8];
            // kd descending -> dd ascending: dependent acc updates spaced apart
#pragma unroll
            for (int kd = 6; kd >= 0; kd--) {
                const int dd = zi - kd;
                if (dd >= 0 && dd < 8)
                    acc7[dd] = __builtin_amdgcn_mfma_f32_16x16x32_bf16(
                        A7k[kd], B, acc7[dd], 0, 0, 0);
            }
            if (has3) {
#pragma unroll
                for (int kd3 = 2; kd3 >= 0; kd3--) {
                    const int dd = zi - 2 - kd3;
                    if (dd >= 0 && dd < 8)
                        acc3[dd] = __builtin_amdgcn_mfma_f32_16x16x32_bf16(
                            A3k[kd3], B, acc3[dd], 0, 0, 0);
                }
            }
        }
    }

    // ---- epilogue: C/D layout col(n=h)=lane&15, row(m=w)=(lane>>4)*4+reg ----
#pragma unroll
    for (int dd = 0; dd < 8; dd++) {
        int d = d0 + zbase + dd;
        size_t off = ((size_t)(nb * Cc + c) * Dd + d) * (Hh * Ww)
                   + (size_t)(h0 + q) * Ww + w0 + p * 4;
        float4 xv = *(const float4*)(x + off);
        float o[4];
        float xr[4] = { xv.x, xv.y, xv.z, xv.w };
#pragma unroll
        for (int r = 0; r < 4; r++) {
            float y7 = fmaxf(fmaf(acc7[dd][r], iv7, bb7), 0.f);
            float y3 = fmaxf(fmaf(acc3[dd][r], iv3, bb3), 0.f);
            float y1 = fmaxf(fmaf(xr[r], s1, bb1), 0.f);
            o[r] = fmaxf(xr[r] + y7 + y3 + y1, 0.f);
        }
        *(float4*)(out + off) = make_float4(o[0], o[1], o[2], o[3]);
    }
}

extern "C" void kernel_launch(void* const* d_in, const int* in_sizes, int n_in,
                              void* d_out, int out_size, void* d_ws, size_t ws_size,
                              hipStream_t stream) {
    const float* x  = (const float*)d_in[0];
    const float* w7 = (const float*)d_in[1];
    const float* w3 = (const float*)d_in[2];
    const float* w1 = (const float*)d_in[3];
    const float* g7 = (const float*)d_in[4];
    const float* b7 = (const float*)d_in[5];
    const float* m7 = (const float*)d_in[6];
    const float* v7 = (const float*)d_in[7];
    const float* g3 = (const float*)d_in[8];
    const float* b3 = (const float*)d_in[9];
    const float* m3 = (const float*)d_in[10];
    const float* v3 = (const float*)d_in[11];
    const float* g1 = (const float*)d_in[12];
    const float* b1 = (const float*)d_in[13];
    const float* m1 = (const float*)d_in[14];
    const float* v1 = (const float*)d_in[15];
    float* out = (float*)d_out;

    dim3 grid(128, 64);   // (8 wblk x 8 hblk x 2 dblk) x (n,c)
    dim3 block(256);
    hipLaunchKernelGGL(replk_mfma, grid, block, 0, stream,
                       x, w7, w3, w1, g7, b7, m7, v7, g3, b3, m3, v3,
                       g1, b1, m1, v1, out);
}

// Round 8
// 321.106 us; speedup vs baseline: 3.4543x; 1.0187x over previous
//
#include <hip/hip_runtime.h>
#include <hip/hip_bf16.h>

#define Dd 64
#define Hh 128
#define Ww 128
#define Cc 32

// block tile: 32d x 16h x 16w outputs; wave = 8d x 16h x 16w
#define BD 32
#define BH 16
#define BW 16
#define ZR (BD + 6)        // 38 staged z-planes
#define HR (BH + 6)        // 22 staged h-rows
#define NR (ZR * HR)       // 836 (z,h) rows
#define RCOLS 24           // bf16 cols per row; col = w - w0 + 4 (left halo 4)
#define BLKROW 3
#define NBLK (NR * BLKROW) // 2508 16B blocks to stage

typedef __attribute__((ext_vector_type(8))) short short8;   // 8 bf16 (4 VGPR)
typedef __attribute__((ext_vector_type(4))) float floatx4;  // MFMA acc

static __device__ __forceinline__ unsigned short f2bf(float f) {
    unsigned u = __builtin_bit_cast(unsigned, f);
    u += 0x7fffu + ((u >> 16) & 1u);   // RNE
    return (unsigned short)(u >> 16);
}

static __device__ __forceinline__ unsigned pk2(float a, float b) {
    union { __hip_bfloat162 h; unsigned u; } cv;
    cv.h = __float22bfloat162_rn(make_float2(a, b));   // v_cvt_pk_bf16_f32
    return cv.u;
}

// Load an A-fragment: 4 aligned b32 LDS reads, no shifts (even/odd dual copy).
static __device__ __forceinline__ short8 loadfrag(const unsigned* wp, int u32off) {
    union { unsigned u[4]; short8 s; } cv;
    cv.u[0] = wp[u32off]; cv.u[1] = wp[u32off + 1];
    cv.u[2] = wp[u32off + 2]; cv.u[3] = wp[u32off + 3];
    return cv.s;
}

__global__ __launch_bounds__(256, 3) void replk_mfma(
    const float* __restrict__ x,
    const float* __restrict__ w7, const float* __restrict__ w3, const float* __restrict__ w1,
    const float* __restrict__ g7, const float* __restrict__ b7, const float* __restrict__ m7, const float* __restrict__ v7,
    const float* __restrict__ g3, const float* __restrict__ b3, const float* __restrict__ m3, const float* __restrict__ v3,
    const float* __restrict__ g1, const float* __restrict__ b1, const float* __restrict__ m1, const float* __restrict__ v1,
    float* __restrict__ out)
{
    __shared__ __align__(16) unsigned short tile[NR * RCOLS];  // 39.2 KB; 48B pitch
    __shared__ __align__(16) unsigned short wboth[58 * 96];    // 10.9 KB: [pl][even/odd][48]

    const int tid = threadIdx.x;

    // XCD-aware swizzle: 8192 blocks, 8 XCDs, 1024 contiguous per XCD
    // => all 128 tiles of a (n,c) slab land on one XCD (halo L2 reuse).
    const unsigned lid = blockIdx.x;
    const unsigned nl = (lid & 7u) * 1024u + (lid >> 3);
    const int bx = nl & 127;
    const int slab = nl >> 7;
    const int c = slab & 31;
    const int nb = slab >> 5;
    const int w0 = (bx & 7) * BW;
    const int h0 = ((bx >> 3) & 7) * BH;
    const int d0 = (bx >> 6) * BD;

    const float* xc = x + (size_t)(nb * Cc + c) * (Dd * Hh * Ww);

    // ---- stage zero-padded weight windows, even + odd-shifted copies ----
    // Wpad7[i] = wt7[i-16] for i-16 in [0,7); Wpad3[i] = wt3[i-18] for [0,3).
    // (band shift +1 vs halo-3 because staged col = w - w0 + 4)
    for (int e = tid; e < 58 * 96; e += 256) {
        int pl = e / 96, r = e - pl * 96;
        int iw = (r < 48) ? r : (r - 47);   // odd copy slot s holds Wpad[s+1]
        unsigned short v = 0;
        if (pl < 49) {
            int t = iw - 16;
            if (t >= 0 && t < 7)
                v = f2bf(w7[c * 343 + (pl / 7) * 49 + (pl % 7) * 7 + t]);
        } else {
            int p3 = pl - 49;
            int t = iw - 18;
            if (t >= 0 && t < 3)
                v = f2bf(w3[c * 27 + (p3 / 3) * 9 + (p3 % 3) * 3 + t]);
        }
        wboth[e] = v;
    }

    // ---- stage input tile fp32 -> bf16 (cvt_pk), 24 cols/row, left halo 4 ----
#pragma unroll
    for (int it = 0; it < 10; it++) {
        int s = tid + it * 256;
        if (s < NBLK) {
            int R = s / BLKROW, bl = s - R * BLKROW;
            int zi = R / HR, hr = R - zi * HR;
            int gz = d0 - 3 + zi, gh = h0 - 3 + hr, gw0 = w0 - 4 + bl * 8;
            float v[8];
#pragma unroll
            for (int j = 0; j < 8; j++) v[j] = 0.f;
            if ((unsigned)gz < (unsigned)Dd && (unsigned)gh < (unsigned)Hh) {
                const float* src = xc + ((size_t)gz * Hh + gh) * Ww + gw0;
                if (gw0 >= 0 && gw0 + 8 <= Ww) {
                    float4 a = *(const float4*)src;
                    float4 b = *(const float4*)(src + 4);
                    v[0] = a.x; v[1] = a.y; v[2] = a.z; v[3] = a.w;
                    v[4] = b.x; v[5] = b.y; v[6] = b.z; v[7] = b.w;
                } else {
#pragma unroll
                    for (int j = 0; j < 8; j++) {
                        int gw = gw0 + j;
                        if ((unsigned)gw < (unsigned)Ww) v[j] = src[j];
                    }
                }
            }
            uint4 pk;
            pk.x = pk2(v[0], v[1]);
            pk.y = pk2(v[2], v[3]);
            pk.z = pk2(v[4], v[5]);
            pk.w = pk2(v[6], v[7]);
            *(uint4*)&tile[R * RCOLS + bl * 8] = pk;
        }
    }

    // BN constants (wave-uniform)
    const float eps = 1e-5f;
    const float iv7 = g7[c] / sqrtf(v7[c] + eps);
    const float bb7 = b7[c] - m7[c] * iv7;
    const float iv3 = g3[c] / sqrtf(v3[c] + eps);
    const float bb3 = b3[c] - m3[c] * iv3;
    const float iv1 = g1[c] / sqrtf(v1[c] + eps);
    const float bb1 = b1[c] - m1[c] * iv1;
    const float s1 = w1[c] * iv1;

    __syncthreads();

    const int lane = tid & 63;
    const int wave = tid >> 6;
    const int q = lane & 15;          // n (h-row) for B; m for A
    const int p = lane >> 4;          // k-group
    const int cg = (p == 3) ? 0 : p;  // p=3's A is all-zero; broadcast-alias B read
    const int zbase = wave * 8;       // wave owns d-outputs [zbase, zbase+8)

    // A-fragment u32 offset within a plane pair: even/odd copy select, no shifts
    const int astart = 8 * p - q + 15;            // in [0,40)
    const int au = (astart & 1) * 24 + ((astart & ~1) >> 1);
    const unsigned* wbu = (const unsigned*)wboth;

    floatx4 acc7[8], acc3[8];
#pragma unroll
    for (int i = 0; i < 8; i++) { acc7[i] = (floatx4)0.f; acc3[i] = (floatx4)0.f; }

    // ---- kh-outer main loop: 10 A-frags live, B row loaded once per zi ----
#pragma unroll 1
    for (int kh = 0; kh < 7; kh++) {
        short8 A7k[7];
#pragma unroll
        for (int kd = 0; kd < 7; kd++)
            A7k[kd] = loadfrag(wbu, (kd * 7 + kh) * 48 + au);

        const bool has3 = (kh >= 2) && (kh < 5);
        short8 A3k[3] = {};
        if (has3) {
            const int kh3 = kh - 2;
#pragma unroll
            for (int kd3 = 0; kd3 < 3; kd3++)
                A3k[kd3] = loadfrag(wbu, (49 + kd3 * 3 + kh3) * 48 + au);
        }

#pragma unroll
        for (int zi = 0; zi < 14; zi++) {
            const int R = (zbase + zi) * HR + q + kh;
            short8 B = *(const short8*)&tile[R * RCOLS + cg * 8];
            __builtin_amdgcn_s_setprio(1);
#pragma unroll
            for (int kd = 6; kd >= 0; kd--) {
                const int dd = zi - kd;
                if (dd >= 0 && dd < 8)
                    acc7[dd] = __builtin_amdgcn_mfma_f32_16x16x32_bf16(
                        A7k[kd], B, acc7[dd], 0, 0, 0);
            }
            if (has3) {
#pragma unroll
                for (int kd3 = 2; kd3 >= 0; kd3--) {
                    const int dd = zi - 2 - kd3;
                    if (dd >= 0 && dd < 8)
                        acc3[dd] = __builtin_amdgcn_mfma_f32_16x16x32_bf16(
                            A3k[kd3], B, acc3[dd], 0, 0, 0);
                }
            }
            __builtin_amdgcn_s_setprio(0);
        }
    }

    // ---- epilogue: residual x read from LDS tile (bf16), no global re-read ----
    // C/D layout: col(n=h)=lane&15, row(m=w)=(lane>>4)*4+reg; center col = m+4
#pragma unroll
    for (int dd = 0; dd < 8; dd++) {
        int d = d0 + zbase + dd;
        const int R = (zbase + dd + 3) * HR + (q + 3);
        uint2 u = *(const uint2*)&tile[R * RCOLS + 4 * p + 4];   // 8B-aligned
        float xr[4];
        xr[0] = __builtin_bit_cast(float, u.x << 16);
        xr[1] = __builtin_bit_cast(float, u.x & 0xffff0000u);
        xr[2] = __builtin_bit_cast(float, u.y << 16);
        xr[3] = __builtin_bit_cast(float, u.y & 0xffff0000u);

        size_t off = ((size_t)(nb * Cc + c) * Dd + d) * (Hh * Ww)
                   + (size_t)(h0 + q) * Ww + w0 + p * 4;
        float o[4];
#pragma unroll
        for (int r = 0; r < 4; r++) {
            float y7 = fmaxf(fmaf(acc7[dd][r], iv7, bb7), 0.f);
            float y3 = fmaxf(fmaf(acc3[dd][r], iv3, bb3), 0.f);
            float y1 = fmaxf(fmaf(xr[r], s1, bb1), 0.f);
            o[r] = fmaxf(xr[r] + y7 + y3 + y1, 0.f);
        }
        *(float4*)(out + off) = make_float4(o[0], o[1], o[2], o[3]);
    }
}

extern "C" void kernel_launch(void* const* d_in, const int* in_sizes, int n_in,
                              void* d_out, int out_size, void* d_ws, size_t ws_size,
                              hipStream_t stream) {
    const float* x  = (const float*)d_in[0];
    const float* w7 = (const float*)d_in[1];
    const float* w3 = (const float*)d_in[2];
    const float* w1 = (const float*)d_in[3];
    const float* g7 = (const float*)d_in[4];
    const float* b7 = (const float*)d_in[5];
    const float* m7 = (const float*)d_in[6];
    const float* v7 = (const float*)d_in[7];
    const float* g3 = (const float*)d_in[8];
    const float* b3 = (const float*)d_in[9];
    const float* m3 = (const float*)d_in[10];
    const float* v3 = (const float*)d_in[11];
    const float* g1 = (const float*)d_in[12];
    const float* b1 = (const float*)d_in[13];
    const float* m1 = (const float*)d_in[14];
    const float* v1 = (const float*)d_in[15];
    float* out = (float*)d_out;

    dim3 grid(8192);   // 1-D; kernel swizzles to (slab, tile) XCD-contiguously
    dim3 block(256);
    hipLaunchKernelGGL(replk_mfma, grid, block, 0, stream,
                       x, w7, w3, w1, g7, b7, m7, v7, g3, b3, m3, v3,
                       g1, b1, m1, v1, out);
}